// Round 2
// baseline (1275.654 us; speedup 1.0000x reference)
//
#include <hip/hip_runtime.h>
#include <math.h>

#define H 512
#define W 512
#define NPIX (H * W)          // 262144
#define NB 2
#define NF 180
#define KS 17
#define KR 8
#define TIN 24                // 8 + 2*KR
#define FPW 45                // filters per wave
#define WGP 48                // padded group stride (floats), 192B-aligned groups

// ---------------- taps (match numpy float64 _gauss1d) ----------------
__global__ void k_taps(float* __restrict__ taps) {
  if (threadIdx.x == 0 && blockIdx.x == 0) {
    {
      double k[5], s = 0.0;
      for (int i = 0; i < 5; i++) { double xv = (double)(i - 2) / 0.4; k[i] = exp(-0.5 * xv * xv); s += k[i]; }
      for (int i = 0; i < 5; i++) taps[i] = (float)(k[i] / s);
    }
    {
      double k[81], s = 0.0;
      for (int i = 0; i < 81; i++) { double xv = (double)(i - 40) / 10.0; k[i] = exp(-0.5 * xv * xv); s += k[i]; }
      for (int i = 0; i < 81; i++) taps[8 + i] = (float)(k[i] / s);
    }
  }
}

// ---------------- weight repack: w3[wv][ky][kx][48] = w[45*wv+j][ky][kx] ----------------
__global__ void k_repack(const float* __restrict__ w, float* __restrict__ w3) {
  int o = blockIdx.x * 256 + threadIdx.x;
  if (o >= 4 * KS * KS * WGP) return;
  int j = o % WGP; int g = o / WGP;
  int kx = g % KS; int t = g / KS;
  int ky = t % KS; int wv = t / KS;
  float v = 0.f;
  if (j < FPW) v = w[(size_t)(FPW * wv + j) * (KS * KS) + ky * KS + kx];
  w3[o] = v;
}

// ---------------- gray ----------------
__global__ void k_gray(const float* __restrict__ x, float* __restrict__ gray) {
  int i = blockIdx.x * blockDim.x + threadIdx.x;
  if (i >= NB * NPIX) return;
  int b = i / NPIX, r = i % NPIX;
  const float* xb = x + (size_t)b * 3 * NPIX;
  gray[i] = 0.2989f * xb[r] + 0.587f * xb[NPIX + r] + 0.114f * xb[2 * NPIX + r];
}

// ---------------- vertical blur, both sigmas fused ----------------
__global__ void k_vblur2(const float* __restrict__ in, float* __restrict__ outA,
                         float* __restrict__ outB, const float* __restrict__ taps) {
  int i = blockIdx.x * blockDim.x + threadIdx.x;
  if (i >= NB * NPIX) return;
  int b = i / NPIX, r = i % NPIX;
  int y = r / W, xx = r % W;
  const float* img = in + (size_t)b * NPIX;
  float a = 0.f;
#pragma unroll
  for (int j = -2; j <= 2; j++) {
    int yy = y + j; yy = yy < 0 ? 0 : (yy > H - 1 ? H - 1 : yy);
    a = fmaf(taps[j + 2], img[yy * W + xx], a);
  }
  float c = 0.f;
  for (int j = -40; j <= 40; j++) {
    int yy = y + j; yy = yy < 0 ? 0 : (yy > H - 1 ? H - 1 : yy);
    c = fmaf(taps[8 + j + 40], img[yy * W + xx], c);
  }
  outA[i] = a;
  outB[i] = c;
}

// ---------------- horizontal blur + DoG ----------------
__global__ void k_hblur_dog(const float* __restrict__ inA, const float* __restrict__ inB,
                            float* __restrict__ dog, const float* __restrict__ taps) {
  int i = blockIdx.x * blockDim.x + threadIdx.x;
  if (i >= NB * NPIX) return;
  int b = i / NPIX, r = i % NPIX;
  int y = r / W, xx = r % W;
  const float* ra = inA + (size_t)b * NPIX + (size_t)y * W;
  const float* rb = inB + (size_t)b * NPIX + (size_t)y * W;
  float a = 0.f;
#pragma unroll
  for (int j = -2; j <= 2; j++) {
    int xc = xx + j; xc = xc < 0 ? 0 : (xc > W - 1 ? W - 1 : xc);
    a = fmaf(taps[j + 2], ra[xc], a);
  }
  float c = 0.f;
  for (int j = -40; j <= 40; j++) {
    int xc = xx + j; xc = xc < 0 ? 0 : (xc > W - 1 ? W - 1 : xc);
    c = fmaf(taps[8 + j + 40], rb[xc], c);
  }
  dog[i] = a - c;
}

// ---------------- main: 180x 17x17 conv + argmax/sum/dist fused ----------------
__launch_bounds__(256)
__global__ void k_gabor(const float* __restrict__ filtered, const float* __restrict__ w3,
                        const float* __restrict__ bins, float* __restrict__ out) {
  __shared__ float stile[TIN * TIN];
  __shared__ float resp[NF][64];
  __shared__ float pm[4][64];
  __shared__ int   pidx[4][64];
  __shared__ float ps[4][64];
  __shared__ float pc[4][64];
  __shared__ int   fidx[64];
  __shared__ float fS[64];

  const int b = blockIdx.z;
  const int ty0 = blockIdx.y * 8, tx0 = blockIdx.x * 8;
  const float* img = filtered + (size_t)b * NPIX;

  // cooperative tile load, zero-padded outside the image (conv pad is zeros)
  for (int i = threadIdx.x; i < TIN * TIN; i += 256) {
    int iy = i / TIN, ix = i % TIN;
    int gy = ty0 + iy - KR, gx = tx0 + ix - KR;
    float v = 0.f;
    if (gy >= 0 && gy < H && gx >= 0 && gx < W) v = img[gy * W + gx];
    stile[i] = v;
  }
  __syncthreads();

  const int lane = threadIdx.x & 63;
  const int wq = __builtin_amdgcn_readfirstlane(threadIdx.x >> 6);  // wave-uniform
  const int py = lane >> 3, px = lane & 7;
  const float* wbase = w3 + (size_t)wq * (KS * KS * WGP);

  float acc[FPW];
#pragma unroll
  for (int f = 0; f < FPW; f++) acc[f] = 0.f;

  for (int ky = 0; ky < KS; ky++) {
    float t[KS];
#pragma unroll
    for (int kx = 0; kx < KS; kx++) t[kx] = stile[(py + ky) * TIN + px + kx];
#pragma unroll
    for (int kx = 0; kx < KS; kx++) {
      const float* wg = wbase + (ky * KS + kx) * WGP;  // 192B-aligned, 45 contiguous
#pragma unroll
      for (int j = 0; j < FPW; j++) {
        acc[j] = fmaf(t[kx], wg[j], acc[j]);
      }
    }
  }

#pragma unroll
  for (int j = 0; j < FPW; j++) resp[wq * FPW + j][lane] = fabsf(acc[j]);
  __syncthreads();

  // ---- epilogue, parallel across all 4 waves ----
  // stage 1: per-wave partial argmax + sum over its 45 filters (per pixel = lane)
  {
    float m = -1.f, S = 0.f;
    int idx = 0;
    for (int j = 0; j < FPW; j++) {
      float r = resp[wq * FPW + j][lane];
      S += r;
      if (r > m) { m = r; idx = wq * FPW + j; }  // first-max-wins within chunk
    }
    pm[wq][lane] = m; pidx[wq][lane] = idx; ps[wq][lane] = S;
  }
  __syncthreads();

  // stage 2: wave 0 combines partials (ties -> smaller index since chunks ordered)
  if (threadIdx.x < 64) {
    const int p = threadIdx.x;
    float m = pm[0][p]; int idx = pidx[0][p]; float S = ps[0][p];
    for (int q = 1; q < 4; q++) {
      float mq = pm[q][p];
      S += ps[q][p];
      if (mq > m) { m = mq; idx = pidx[q][p]; }
    }
    fidx[p] = idx; fS[p] = S;
    float om = (float)idx / 180.0f * 255.0f;
    int y = ty0 + (p >> 3), x = tx0 + (p & 7);
    out[(size_t)b * NPIX + y * W + x] = om;  // orientation_map
  }
  __syncthreads();

  // stage 3: all threads, partial confidence over own 45 filters
  {
    const float PI_F = 3.14159265358979323846f;
    int idx = fidx[lane];
    float om = (float)idx / 180.0f * 255.0f;
    float rad = om / 180.0f * PI_F;
    float C = 0.f;
    for (int j = 0; j < FPW; j++) {
      float bn = bins[wq * FPW + j];
      float dd = rad - bn;
      float d0 = fabsf(dd);
      float d1 = fabsf(dd - PI_F);
      float d2 = fabsf(dd + PI_F);
      float d = fminf(d0, fminf(d1, d2));
      C = fmaf(d * d, resp[wq * FPW + j][lane], C);
    }
    pc[wq][lane] = C;
  }
  __syncthreads();

  // stage 4: wave 0 finalizes confidence
  if (threadIdx.x < 64) {
    const int p = threadIdx.x;
    float C = ((pc[0][p] + pc[1][p]) + pc[2][p]) + pc[3][p];
    int y = ty0 + (p >> 3), x = tx0 + (p & 7);
    out[(size_t)NB * NPIX + (size_t)b * NPIX + y * W + x] = C / fS[p];
  }
}

extern "C" void kernel_launch(void* const* d_in, const int* in_sizes, int n_in,
                              void* d_out, int out_size, void* d_ws, size_t ws_size,
                              hipStream_t stream) {
  const float* x = (const float*)d_in[0];      // [2,3,512,512]
  const float* wts = (const float*)d_in[1];    // [180,1,17,17]
  const float* bins = (const float*)d_in[2];   // [180]
  float* out = (float*)d_out;                  // 524288 orientation + 524288 confidence

  float* ws = (float*)d_ws;
  float* gray = ws;                       // 524288
  float* tmpA = ws + (size_t)NB * NPIX;   // 524288
  float* tmpB = tmpA + (size_t)NB * NPIX; // 524288
  float* dog  = tmpB + (size_t)NB * NPIX; // 524288
  float* taps = dog + (size_t)NB * NPIX;  // 128
  float* w3   = taps + 128;               // 4*17*17*48 = 55488 floats

  k_taps<<<1, 64, 0, stream>>>(taps);

  int nw3 = 4 * KS * KS * WGP;
  k_repack<<<(nw3 + 255) / 256, 256, 0, stream>>>(wts, w3);

  int n = NB * NPIX;
  int blk = 256, grd = (n + blk - 1) / blk;
  k_gray<<<grd, blk, 0, stream>>>(x, gray);
  k_vblur2<<<grd, blk, 0, stream>>>(gray, tmpA, tmpB, taps);
  k_hblur_dog<<<grd, blk, 0, stream>>>(tmpA, tmpB, dog, taps);

  dim3 g(W / 8, H / 8, NB);
  k_gabor<<<g, 256, 0, stream>>>(dog, w3, bins, out);
}

// Round 3
// 260.700 us; speedup vs baseline: 4.8932x; 4.8932x over previous
//
#include <hip/hip_runtime.h>
#include <math.h>
#include <stdint.h>

#define H 512
#define W 512
#define NPIX (H * W)          // 262144
#define NB 2
#define NF 180
#define KS 17
#define WSCALE 1024.0f        // exact power of two; cancels in both outputs

typedef _Float16 half8 __attribute__((ext_vector_type(8)));
typedef float floatx16 __attribute__((ext_vector_type(16)));
typedef uint32_t u32x4 __attribute__((ext_vector_type(4)));

union FragU { u32x4 u; half8 h; };

// ---------------- taps (match numpy float64 _gauss1d) ----------------
__global__ void k_taps(float* __restrict__ taps) {
  if (threadIdx.x == 0 && blockIdx.x == 0) {
    {
      double k[5], s = 0.0;
      for (int i = 0; i < 5; i++) { double xv = (double)(i - 2) / 0.4; k[i] = exp(-0.5 * xv * xv); s += k[i]; }
      for (int i = 0; i < 5; i++) taps[i] = (float)(k[i] / s);
    }
    {
      double k[81], s = 0.0;
      for (int i = 0; i < 81; i++) { double xv = (double)(i - 40) / 10.0; k[i] = exp(-0.5 * xv * xv); s += k[i]; }
      for (int i = 0; i < 81; i++) taps[8 + i] = (float)(k[i] / s);
    }
  }
}

// ---------------- weight repack into MFMA B-fragment order, f16 split ----------------
// Bf layout (u32): chunk c (19): [c*3072 .. ]: h-frags: t*256 + lane*4 + q ; l-frags at +1536
// B[k][n]: lane: n = t*32 + (lane&31), k = 8*(lane>>5) + j, dword q holds j=2q (lo16), j=2q+1 (hi16)
// chunks: c<17: (ky=c, kx=k); c==17: (ky=k, kx=16); c==18: k==0 -> (ky=16,kx=16)
__global__ void k_repackB(const float* __restrict__ w, uint32_t* __restrict__ Bf) {
  int tid = blockIdx.x * 256 + threadIdx.x;
  if (tid >= 19 * 6 * 64 * 4) return;
  int q = tid & 3;
  int lane = (tid >> 2) & 63;
  int ct = tid >> 8;
  int t = ct % 6, c = ct / 6;
  int n = t * 32 + (lane & 31);
  int hf = lane >> 5;
  uint32_t hv = 0, lv = 0;
  for (int s = 0; s < 2; s++) {
    int j = 2 * q + s;
    int k = hf * 8 + j;   // 0..15
    float val = 0.f;
    if (n < NF) {
      if (c < 17)       val = w[n * 289 + c * 17 + k];
      else if (c == 17) val = w[n * 289 + k * 17 + 16];
      else if (k == 0)  val = w[n * 289 + 16 * 17 + 16];
    }
    val *= WSCALE;
    _Float16 hh = (_Float16)val;
    _Float16 ll = (_Float16)(val - (float)hh);
    hv |= (uint32_t)__builtin_bit_cast(uint16_t, hh) << (16 * s);
    lv |= (uint32_t)__builtin_bit_cast(uint16_t, ll) << (16 * s);
  }
  int base = c * 3072;
  int off = t * 256 + lane * 4 + q;
  Bf[base + off] = hv;
  Bf[base + 1536 + off] = lv;
}

// ---------------- gray ----------------
__global__ void k_gray(const float* __restrict__ x, float* __restrict__ gray) {
  int i = blockIdx.x * blockDim.x + threadIdx.x;
  if (i >= NB * NPIX) return;
  int b = i / NPIX, r = i % NPIX;
  const float* xb = x + (size_t)b * 3 * NPIX;
  gray[i] = 0.2989f * xb[r] + 0.587f * xb[NPIX + r] + 0.114f * xb[2 * NPIX + r];
}

// ---------------- vertical blur, both sigmas fused ----------------
__global__ void k_vblur2(const float* __restrict__ in, float* __restrict__ outA,
                         float* __restrict__ outB, const float* __restrict__ taps) {
  int i = blockIdx.x * blockDim.x + threadIdx.x;
  if (i >= NB * NPIX) return;
  int b = i / NPIX, r = i % NPIX;
  int y = r / W, xx = r % W;
  const float* img = in + (size_t)b * NPIX;
  float a = 0.f;
#pragma unroll
  for (int j = -2; j <= 2; j++) {
    int yy = y + j; yy = yy < 0 ? 0 : (yy > H - 1 ? H - 1 : yy);
    a = fmaf(taps[j + 2], img[yy * W + xx], a);
  }
  float c = 0.f;
  for (int j = -40; j <= 40; j++) {
    int yy = y + j; yy = yy < 0 ? 0 : (yy > H - 1 ? H - 1 : yy);
    c = fmaf(taps[8 + j + 40], img[yy * W + xx], c);
  }
  outA[i] = a;
  outB[i] = c;
}

// ---------------- horizontal blur + DoG + f16-split pack ----------------
__global__ void k_hblur_dog(const float* __restrict__ inA, const float* __restrict__ inB,
                            uint32_t* __restrict__ dogp, const float* __restrict__ taps) {
  int i = blockIdx.x * blockDim.x + threadIdx.x;
  if (i >= NB * NPIX) return;
  int b = i / NPIX, r = i % NPIX;
  int y = r / W, xx = r % W;
  const float* ra = inA + (size_t)b * NPIX + (size_t)y * W;
  const float* rb = inB + (size_t)b * NPIX + (size_t)y * W;
  float a = 0.f;
#pragma unroll
  for (int j = -2; j <= 2; j++) {
    int xc = xx + j; xc = xc < 0 ? 0 : (xc > W - 1 ? W - 1 : xc);
    a = fmaf(taps[j + 2], ra[xc], a);
  }
  float c = 0.f;
  for (int j = -40; j <= 40; j++) {
    int xc = xx + j; xc = xc < 0 ? 0 : (xc > W - 1 ? W - 1 : xc);
    c = fmaf(taps[8 + j + 40], rb[xc], c);
  }
  float d = a - c;
  _Float16 hh = (_Float16)d;
  _Float16 ll = (_Float16)(d - (float)hh);
  dogp[i] = ((uint32_t)__builtin_bit_cast(uint16_t, ll) << 16) |
            (uint32_t)__builtin_bit_cast(uint16_t, hh);
}

// ---------------- main: implicit-GEMM MFMA conv + in-register epilogue ----------------
// block: 512 thr = 8 waves; wave w handles output row y0+w, 64 px (2 m-tiles of 32)
// GEMM: N=192 (6 n-tiles), K chunks: 17 row-chunks (ky=c, kx 0..15) + 2 col-chunks (kx=16)
__launch_bounds__(512)
__global__ void k_conv(const uint32_t* __restrict__ dogp,
                       const uint32_t* __restrict__ Bf,
                       const float* __restrict__ bins,
                       float* __restrict__ out) {
  __shared__ uint32_t stile[24 * 80];   // packed (hi|lo f16) input rows
  __shared__ uint32_t Blds[2][3072];    // double-buffered B chunk (h:1536, l:1536)

  const int b  = blockIdx.z;
  const int y0 = blockIdx.y * 8;
  const int x0 = blockIdx.x * 64;
  const int tid = threadIdx.x;
  const int lane = tid & 63;
  const int wv = __builtin_amdgcn_readfirstlane(tid >> 6);  // 0..7
  const int nl = lane & 31;
  const int half = lane >> 5;

  // stage input tile rows y0-8 .. y0+15, x0-8 .. x0+71 (zero-padded)
  const uint32_t* dgb = dogp + (size_t)b * NPIX;
  for (int i = tid; i < 24 * 80; i += 512) {
    int ry = i / 80, rx = i % 80;
    int gy = y0 + ry - 8, gx = x0 + rx - 8;
    uint32_t v = 0;
    if (gy >= 0 && gy < H && gx >= 0 && gx < W) v = dgb[gy * W + gx];
    stile[i] = v;
  }
  // stage B chunk 0
  for (int i = tid; i < 3072; i += 512) Blds[0][i] = Bf[i];
  __syncthreads();

  floatx16 acc[2][6];
#pragma unroll
  for (int mt = 0; mt < 2; mt++)
#pragma unroll
    for (int t = 0; t < 6; t++)
#pragma unroll
      for (int r = 0; r < 16; r++) acc[mt][t][r] = 0.f;

  int buf = 0;
  for (int c = 0; c < 19; c++) {
    // T14: issue next-chunk global loads early
    uint32_t pf[6];
    if (c + 1 < 19) {
      const uint32_t* src = Bf + (size_t)(c + 1) * 3072;
#pragma unroll
      for (int i = 0; i < 6; i++) pf[i] = src[tid + i * 512];
    }

    // build A fragments (hi & lo) for both m-tiles
    uint32_t ah[2][4], al[2][4];
    if (c < 17) {
#pragma unroll
      for (int mt = 0; mt < 2; mt++) {
        const uint32_t* rp = &stile[(wv + c) * 80 + mt * 32 + nl + half * 8];
        uint32_t d[8];
#pragma unroll
        for (int j = 0; j < 8; j++) d[j] = rp[j];
#pragma unroll
        for (int q = 0; q < 4; q++) {
          ah[mt][q] = __builtin_amdgcn_perm(d[2 * q + 1], d[2 * q], 0x05040100u);
          al[mt][q] = __builtin_amdgcn_perm(d[2 * q + 1], d[2 * q], 0x07060302u);
        }
      }
    } else {
      int kyb = (c - 17) * 16 + half * 8;
#pragma unroll
      for (int mt = 0; mt < 2; mt++) {
        uint32_t d[8];
#pragma unroll
        for (int j = 0; j < 8; j++) {
          int ky = kyb + j; if (ky > 16) ky = 16;   // clamped reads are killed by B=0
          d[j] = stile[(wv + ky) * 80 + mt * 32 + nl + 16];
        }
#pragma unroll
        for (int q = 0; q < 4; q++) {
          ah[mt][q] = __builtin_amdgcn_perm(d[2 * q + 1], d[2 * q], 0x05040100u);
          al[mt][q] = __builtin_amdgcn_perm(d[2 * q + 1], d[2 * q], 0x07060302u);
        }
      }
    }

    // MFMA: per n-tile read Bh/Bl once, 3-term split accumulate
#pragma unroll
    for (int t = 0; t < 6; t++) {
      FragU bh, bl;
      bh.u = *(const u32x4*)&Blds[buf][t * 256 + lane * 4];
      bl.u = *(const u32x4*)&Blds[buf][1536 + t * 256 + lane * 4];
#pragma unroll
      for (int mt = 0; mt < 2; mt++) {
        FragU fh, fl;
        fh.u.x = ah[mt][0]; fh.u.y = ah[mt][1]; fh.u.z = ah[mt][2]; fh.u.w = ah[mt][3];
        fl.u.x = al[mt][0]; fl.u.y = al[mt][1]; fl.u.z = al[mt][2]; fl.u.w = al[mt][3];
        acc[mt][t] = __builtin_amdgcn_mfma_f32_32x32x16_f16(fh.h, bh.h, acc[mt][t], 0, 0, 0);
        acc[mt][t] = __builtin_amdgcn_mfma_f32_32x32x16_f16(fl.h, bh.h, acc[mt][t], 0, 0, 0);
        acc[mt][t] = __builtin_amdgcn_mfma_f32_32x32x16_f16(fh.h, bl.h, acc[mt][t], 0, 0, 0);
      }
    }

    // write prefetched chunk after compute
    if (c + 1 < 19) {
#pragma unroll
      for (int i = 0; i < 6; i++) Blds[buf ^ 1][tid + i * 512] = pf[i];
    }
    __syncthreads();
    buf ^= 1;
  }

  // ---- in-register epilogue ----
  const float PI_F = 3.14159265358979323846f;
  float bn[6];
#pragma unroll
  for (int t = 0; t < 6; t++) {
    int n = t * 32 + nl;
    bn[t] = (n < NF) ? bins[n] : 0.f;
  }

#pragma unroll
  for (int mt = 0; mt < 2; mt++) {
#pragma unroll
    for (int r = 0; r < 16; r++) {
      float v[6];
      float S = 0.f, m = -1.f;
      int bt = 0;
#pragma unroll
      for (int t = 0; t < 6; t++) {
        v[t] = fabsf(acc[mt][t][r]);
        S += v[t];
        if (v[t] > m) { m = v[t]; bt = t; }   // first-max within lane (n ascending with t)
      }
      int n = bt * 32 + nl;
      // cross-lane reduce over the 32-lane n-group (argmax w/ smaller-index tie-break, sum)
#pragma unroll
      for (int msk = 1; msk < 32; msk <<= 1) {
        float vo = __shfl_xor(m, msk);
        int   no = __shfl_xor(n, msk);
        float So = __shfl_xor(S, msk);
        bool take = (vo > m) || (vo == m && no < n);
        m = take ? vo : m;
        n = take ? no : n;
        S += So;
      }
      float om  = (float)n / 180.0f * 255.0f;
      float rad = om / 180.0f * PI_F;
      float C = 0.f;
#pragma unroll
      for (int t = 0; t < 6; t++) {
        float dd = rad - bn[t];
        float d0 = fabsf(dd);
        float d1 = fabsf(dd - PI_F);
        float d2 = fabsf(dd + PI_F);
        float d = fminf(d0, fminf(d1, d2));
        C = fmaf(d * d, v[t], C);
      }
#pragma unroll
      for (int msk = 1; msk < 32; msk <<= 1) C += __shfl_xor(C, msk);
      if (nl == 0) {
        int px = mt * 32 + (r & 3) + 8 * (r >> 2) + 4 * half;
        int y = y0 + wv, x = x0 + px;
        out[(size_t)b * NPIX + (size_t)y * W + x] = om;
        out[(size_t)NB * NPIX + (size_t)b * NPIX + (size_t)y * W + x] = C / S;
      }
    }
  }
}

extern "C" void kernel_launch(void* const* d_in, const int* in_sizes, int n_in,
                              void* d_out, int out_size, void* d_ws, size_t ws_size,
                              hipStream_t stream) {
  const float* x = (const float*)d_in[0];      // [2,3,512,512]
  const float* wts = (const float*)d_in[1];    // [180,1,17,17]
  const float* bins = (const float*)d_in[2];   // [180]
  float* out = (float*)d_out;

  float* ws = (float*)d_ws;
  float* gray = ws;                                 // 524288 f32
  float* tmpA = ws + (size_t)NB * NPIX;             // 524288 f32
  float* tmpB = tmpA + (size_t)NB * NPIX;           // 524288 f32
  uint32_t* dogp = (uint32_t*)(tmpB + (size_t)NB * NPIX);  // 524288 u32
  float* taps = (float*)(dogp + (size_t)NB * NPIX); // 128 f32
  uint32_t* Bf = (uint32_t*)(taps + 128);           // 19*3072 u32

  k_taps<<<1, 64, 0, stream>>>(taps);
  k_repackB<<<114, 256, 0, stream>>>(wts, Bf);

  int n = NB * NPIX;
  int blk = 256, grd = (n + blk - 1) / blk;
  k_gray<<<grd, blk, 0, stream>>>(x, gray);
  k_vblur2<<<grd, blk, 0, stream>>>(gray, tmpA, tmpB, taps);
  k_hblur_dog<<<grd, blk, 0, stream>>>(tmpA, tmpB, dogp, taps);

  dim3 g(W / 64, H / 8, NB);
  k_conv<<<g, 512, 0, stream>>>(dogp, Bf, bins, out);
}

// Round 4
// 248.792 us; speedup vs baseline: 5.1274x; 1.0479x over previous
//
#include <hip/hip_runtime.h>
#include <math.h>
#include <stdint.h>

#define H 512
#define W 512
#define NPIX (H * W)          // 262144
#define NB 2
#define NF 180
#define KS 17
#define WSCALE 1024.0f        // exact power of two; cancels in both outputs

typedef _Float16 half8 __attribute__((ext_vector_type(8)));
typedef float floatx16 __attribute__((ext_vector_type(16)));
typedef uint32_t u32x4 __attribute__((ext_vector_type(4)));

union FragU { u32x4 u; half8 h; };

__device__ inline void gl_lds16(const uint32_t* g, uint32_t* l) {
  __builtin_amdgcn_global_load_lds((const __attribute__((address_space(1))) void*)g,
                                   (__attribute__((address_space(3))) void*)l, 16, 0, 0);
}

// ---------------- taps (match numpy float64 _gauss1d) ----------------
__global__ void k_taps(float* __restrict__ taps) {
  if (threadIdx.x == 0 && blockIdx.x == 0) {
    {
      double k[5], s = 0.0;
      for (int i = 0; i < 5; i++) { double xv = (double)(i - 2) / 0.4; k[i] = exp(-0.5 * xv * xv); s += k[i]; }
      for (int i = 0; i < 5; i++) taps[i] = (float)(k[i] / s);
    }
    {
      double k[81], s = 0.0;
      for (int i = 0; i < 81; i++) { double xv = (double)(i - 40) / 10.0; k[i] = exp(-0.5 * xv * xv); s += k[i]; }
      for (int i = 0; i < 81; i++) taps[8 + i] = (float)(k[i] / s);
    }
  }
}

// ---------------- weight repack into MFMA B-fragment order, f16 split ----------------
// Bf layout (u32): chunk c (19): [c*3072 .. ]: h-frags: t*256 + lane*4 + q ; l-frags at +1536
// B[k][n]: lane: n = t*32 + (lane&31), k = 8*(lane>>5) + j, dword q holds j=2q (lo16), j=2q+1 (hi16)
// chunks: c<17: (ky=c, kx=k); c==17: (ky=k, kx=16); c==18: k==0 -> (ky=16,kx=16)
__global__ void k_repackB(const float* __restrict__ w, uint32_t* __restrict__ Bf) {
  int tid = blockIdx.x * 256 + threadIdx.x;
  if (tid >= 19 * 6 * 64 * 4) return;
  int q = tid & 3;
  int lane = (tid >> 2) & 63;
  int ct = tid >> 8;
  int t = ct % 6, c = ct / 6;
  int n = t * 32 + (lane & 31);
  int hf = lane >> 5;
  uint32_t hv = 0, lv = 0;
  for (int s = 0; s < 2; s++) {
    int j = 2 * q + s;
    int k = hf * 8 + j;   // 0..15
    float val = 0.f;
    if (n < NF) {
      if (c < 17)       val = w[n * 289 + c * 17 + k];
      else if (c == 17) val = w[n * 289 + k * 17 + 16];
      else if (k == 0)  val = w[n * 289 + 16 * 17 + 16];
    }
    val *= WSCALE;
    _Float16 hh = (_Float16)val;
    _Float16 ll = (_Float16)(val - (float)hh);
    hv |= (uint32_t)__builtin_bit_cast(uint16_t, hh) << (16 * s);
    lv |= (uint32_t)__builtin_bit_cast(uint16_t, ll) << (16 * s);
  }
  int base = c * 3072;
  int off = t * 256 + lane * 4 + q;
  Bf[base + off] = hv;
  Bf[base + 1536 + off] = lv;
}

// ---------------- gray ----------------
__global__ void k_gray(const float* __restrict__ x, float* __restrict__ gray) {
  int i = blockIdx.x * blockDim.x + threadIdx.x;
  if (i >= NB * NPIX) return;
  int b = i / NPIX, r = i % NPIX;
  const float* xb = x + (size_t)b * 3 * NPIX;
  gray[i] = 0.2989f * xb[r] + 0.587f * xb[NPIX + r] + 0.114f * xb[2 * NPIX + r];
}

// ---------------- vertical blur, both sigmas fused ----------------
__global__ void k_vblur2(const float* __restrict__ in, float* __restrict__ outA,
                         float* __restrict__ outB, const float* __restrict__ taps) {
  int i = blockIdx.x * blockDim.x + threadIdx.x;
  if (i >= NB * NPIX) return;
  int b = i / NPIX, r = i % NPIX;
  int y = r / W, xx = r % W;
  const float* img = in + (size_t)b * NPIX;
  float a = 0.f;
#pragma unroll
  for (int j = -2; j <= 2; j++) {
    int yy = y + j; yy = yy < 0 ? 0 : (yy > H - 1 ? H - 1 : yy);
    a = fmaf(taps[j + 2], img[yy * W + xx], a);
  }
  float c = 0.f;
  for (int j = -40; j <= 40; j++) {
    int yy = y + j; yy = yy < 0 ? 0 : (yy > H - 1 ? H - 1 : yy);
    c = fmaf(taps[8 + j + 40], img[yy * W + xx], c);
  }
  outA[i] = a;
  outB[i] = c;
}

// ---------------- horizontal blur + DoG + f16-split pack ----------------
__global__ void k_hblur_dog(const float* __restrict__ inA, const float* __restrict__ inB,
                            uint32_t* __restrict__ dogp, const float* __restrict__ taps) {
  int i = blockIdx.x * blockDim.x + threadIdx.x;
  if (i >= NB * NPIX) return;
  int b = i / NPIX, r = i % NPIX;
  int y = r / W, xx = r % W;
  const float* ra = inA + (size_t)b * NPIX + (size_t)y * W;
  const float* rb = inB + (size_t)b * NPIX + (size_t)y * W;
  float a = 0.f;
#pragma unroll
  for (int j = -2; j <= 2; j++) {
    int xc = xx + j; xc = xc < 0 ? 0 : (xc > W - 1 ? W - 1 : xc);
    a = fmaf(taps[j + 2], ra[xc], a);
  }
  float c = 0.f;
  for (int j = -40; j <= 40; j++) {
    int xc = xx + j; xc = xc < 0 ? 0 : (xc > W - 1 ? W - 1 : xc);
    c = fmaf(taps[8 + j + 40], rb[xc], c);
  }
  float d = a - c;
  _Float16 hh = (_Float16)d;
  _Float16 ll = (_Float16)(d - (float)hh);
  dogp[i] = ((uint32_t)__builtin_bit_cast(uint16_t, ll) << 16) |
            (uint32_t)__builtin_bit_cast(uint16_t, hh);
}

// ---------------- main: implicit-GEMM MFMA conv + in-register epilogue ----------------
// block: 256 thr = 4 waves; wave wv -> output row y0+wv, 64 px (2 m-tiles of 32)
// GEMM: N=192 (6 n-tiles), K chunks: 17 row-chunks (ky=c, kx 0..15) + 2 col-chunks (kx=16)
// B chunks staged global->LDS via async global_load_lds, double-buffered.
__launch_bounds__(256, 2)
__global__ void k_conv(const uint32_t* __restrict__ dogp,
                       const uint32_t* __restrict__ Bf,
                       const float* __restrict__ bins,
                       float* __restrict__ out) {
  __shared__ uint32_t stile[20 * 80];   // packed (hi|lo f16) input rows
  __shared__ uint32_t Blds[2][3072];    // double-buffered B chunk (h:1536, l:1536)

  const int b  = blockIdx.z;
  const int y0 = blockIdx.y * 4;
  const int x0 = blockIdx.x * 64;
  const int tid = threadIdx.x;
  const int lane = tid & 63;
  const int wv = __builtin_amdgcn_readfirstlane(tid >> 6);  // 0..3
  const int nl = lane & 31;
  const int half = lane >> 5;

  // stage input tile rows y0-8 .. y0+11, x0-8 .. x0+71 (zero-padded)
  const uint32_t* dgb = dogp + (size_t)b * NPIX;
  for (int i = tid; i < 20 * 80; i += 256) {
    int ry = i / 80, rx = i % 80;
    int gy = y0 + ry - 8, gx = x0 + rx - 8;
    uint32_t v = 0;
    if (gy >= 0 && gy < H && gx >= 0 && gx < W) v = dgb[gy * W + gx];
    stile[i] = v;
  }
  // stage B chunk 0 (async -> LDS)
  {
    const uint32_t* src = Bf + (size_t)tid * 4;
    uint32_t* dst = &Blds[0][tid * 4];
    gl_lds16(src, dst);
    gl_lds16(src + 1024, dst + 1024);
    gl_lds16(src + 2048, dst + 2048);
  }
  asm volatile("s_waitcnt vmcnt(0)" ::: "memory");
  __syncthreads();

  floatx16 acc[2][6];
#pragma unroll
  for (int mt = 0; mt < 2; mt++)
#pragma unroll
    for (int t = 0; t < 6; t++)
#pragma unroll
      for (int r = 0; r < 16; r++) acc[mt][t][r] = 0.f;

  int buf = 0;
  for (int c = 0; c < 19; c++) {
    // issue next-chunk staging into the other buffer (safe: everyone is done
    // reading buf^1 as of the barrier that ended the previous iteration)
    if (c + 1 < 19) {
      const uint32_t* src = Bf + (size_t)(c + 1) * 3072 + (size_t)tid * 4;
      uint32_t* dst = &Blds[buf ^ 1][tid * 4];
      gl_lds16(src, dst);
      gl_lds16(src + 1024, dst + 1024);
      gl_lds16(src + 2048, dst + 2048);
    }

    // build A fragments (hi & lo) for both m-tiles
    uint32_t ah[2][4], al[2][4];
    if (c < 17) {
#pragma unroll
      for (int mt = 0; mt < 2; mt++) {
        const uint32_t* rp = &stile[(wv + c) * 80 + mt * 32 + nl + half * 8];
        uint32_t d[8];
#pragma unroll
        for (int j = 0; j < 8; j++) d[j] = rp[j];
#pragma unroll
        for (int q = 0; q < 4; q++) {
          ah[mt][q] = __builtin_amdgcn_perm(d[2 * q + 1], d[2 * q], 0x05040100u);
          al[mt][q] = __builtin_amdgcn_perm(d[2 * q + 1], d[2 * q], 0x07060302u);
        }
      }
    } else {
      int kyb = (c - 17) * 16 + half * 8;
#pragma unroll
      for (int mt = 0; mt < 2; mt++) {
        uint32_t d[8];
#pragma unroll
        for (int j = 0; j < 8; j++) {
          int ky = kyb + j; if (ky > 16) ky = 16;   // clamped reads are killed by B=0
          d[j] = stile[(wv + ky) * 80 + mt * 32 + nl + 16];
        }
#pragma unroll
        for (int q = 0; q < 4; q++) {
          ah[mt][q] = __builtin_amdgcn_perm(d[2 * q + 1], d[2 * q], 0x05040100u);
          al[mt][q] = __builtin_amdgcn_perm(d[2 * q + 1], d[2 * q], 0x07060302u);
        }
      }
    }

    // MFMA: per n-tile read Bh/Bl once, 3-term split accumulate
#pragma unroll
    for (int t = 0; t < 6; t++) {
      FragU bh, bl;
      bh.u = *(const u32x4*)&Blds[buf][t * 256 + lane * 4];
      bl.u = *(const u32x4*)&Blds[buf][1536 + t * 256 + lane * 4];
#pragma unroll
      for (int mt = 0; mt < 2; mt++) {
        FragU fh, fl;
        fh.u.x = ah[mt][0]; fh.u.y = ah[mt][1]; fh.u.z = ah[mt][2]; fh.u.w = ah[mt][3];
        fl.u.x = al[mt][0]; fl.u.y = al[mt][1]; fl.u.z = al[mt][2]; fl.u.w = al[mt][3];
        acc[mt][t] = __builtin_amdgcn_mfma_f32_32x32x16_f16(fh.h, bh.h, acc[mt][t], 0, 0, 0);
        acc[mt][t] = __builtin_amdgcn_mfma_f32_32x32x16_f16(fl.h, bh.h, acc[mt][t], 0, 0, 0);
        acc[mt][t] = __builtin_amdgcn_mfma_f32_32x32x16_f16(fh.h, bl.h, acc[mt][t], 0, 0, 0);
      }
    }

    asm volatile("s_waitcnt vmcnt(0)" ::: "memory");
    __syncthreads();
    buf ^= 1;
  }

  // ---- in-register epilogue ----
  const float PI_F = 3.14159265358979323846f;
  float bn[6];
#pragma unroll
  for (int t = 0; t < 6; t++) {
    int n = t * 32 + nl;
    bn[t] = (n < NF) ? bins[n] : 0.f;
  }

#pragma unroll
  for (int mt = 0; mt < 2; mt++) {
#pragma unroll
    for (int r = 0; r < 16; r++) {
      float v[6];
      float S = 0.f, m = -1.f;
      int bt = 0;
#pragma unroll
      for (int t = 0; t < 6; t++) {
        v[t] = fabsf(acc[mt][t][r]);
        S += v[t];
        if (v[t] > m) { m = v[t]; bt = t; }   // first-max within lane (n ascending with t)
      }
      int n = bt * 32 + nl;
      // cross-lane reduce over the 32-lane n-group (argmax w/ smaller-index tie-break, sum)
#pragma unroll
      for (int msk = 1; msk < 32; msk <<= 1) {
        float vo = __shfl_xor(m, msk);
        int   no = __shfl_xor(n, msk);
        float So = __shfl_xor(S, msk);
        bool take = (vo > m) || (vo == m && no < n);
        m = take ? vo : m;
        n = take ? no : n;
        S += So;
      }
      float om  = (float)n / 180.0f * 255.0f;
      float rad = om / 180.0f * PI_F;
      float C = 0.f;
#pragma unroll
      for (int t = 0; t < 6; t++) {
        float dd = rad - bn[t];
        float d0 = fabsf(dd);
        float d1 = fabsf(dd - PI_F);
        float d2 = fabsf(dd + PI_F);
        float d = fminf(d0, fminf(d1, d2));
        C = fmaf(d * d, v[t], C);
      }
#pragma unroll
      for (int msk = 1; msk < 32; msk <<= 1) C += __shfl_xor(C, msk);
      if (nl == 0) {
        int px = mt * 32 + (r & 3) + 8 * (r >> 2) + 4 * half;
        int y = y0 + wv, x = x0 + px;
        out[(size_t)b * NPIX + (size_t)y * W + x] = om;
        out[(size_t)NB * NPIX + (size_t)b * NPIX + (size_t)y * W + x] = C / S;
      }
    }
  }
}

extern "C" void kernel_launch(void* const* d_in, const int* in_sizes, int n_in,
                              void* d_out, int out_size, void* d_ws, size_t ws_size,
                              hipStream_t stream) {
  const float* x = (const float*)d_in[0];      // [2,3,512,512]
  const float* wts = (const float*)d_in[1];    // [180,1,17,17]
  const float* bins = (const float*)d_in[2];   // [180]
  float* out = (float*)d_out;

  float* ws = (float*)d_ws;
  float* gray = ws;                                 // 524288 f32
  float* tmpA = ws + (size_t)NB * NPIX;             // 524288 f32
  float* tmpB = tmpA + (size_t)NB * NPIX;           // 524288 f32
  uint32_t* dogp = (uint32_t*)(tmpB + (size_t)NB * NPIX);  // 524288 u32
  float* taps = (float*)(dogp + (size_t)NB * NPIX); // 128 f32
  uint32_t* Bf = (uint32_t*)(taps + 128);           // 19*3072 u32

  k_taps<<<1, 64, 0, stream>>>(taps);
  k_repackB<<<114, 256, 0, stream>>>(wts, Bf);

  int n = NB * NPIX;
  int blk = 256, grd = (n + blk - 1) / blk;
  k_gray<<<grd, blk, 0, stream>>>(x, gray);
  k_vblur2<<<grd, blk, 0, stream>>>(gray, tmpA, tmpB, taps);
  k_hblur_dog<<<grd, blk, 0, stream>>>(tmpA, tmpB, dogp, taps);

  dim3 g(W / 64, H / 4, NB);
  k_conv<<<g, 256, 0, stream>>>(dogp, Bf, bins, out);
}